// Round 5
// baseline (3777.977 us; speedup 1.0000x reference)
//
#include <hip/hip_runtime.h>
#include <stdint.h>

// Problem constants
#define B_TOT    65536
#define H_DIM    256
#define E_DIM    64
#define P_STEPS  12

// Config: 32-row batch tile, 4 waves, 2 WGs/CU (VGPR-limited), no spills
#define BT       32
#define NTHREADS 256
#define MT       2          // 16-row M tiles per wave (BT/16)
#define NPASS    4          // hidden passes (64 hidden cols each)
#define KK1      10         // K=320 / 32
#define KK2      8          // K=256 / 32
#define NIT      (NPASS * KK1)   // 40 flat GEMM1 iters

#define XSTRIDE  328        // 320 + 8 pad (bf16 elems)
#define HSTRIDE  264        // 256 + 8 pad

// workspace layout (bytes) -- weights replicated x8, selected by HW XCC_ID
#define WG_OFS        0
#define WG_REPL_BYTES (640 * 1024)                  // 640 frags x 1KB
#define WG_TOT        (8 * WG_REPL_BYTES)           // 5242880
#define W2_OFS        WG_TOT
#define W2_REPL_BYTES (72 * 1024)                   // 72 frags x 1KB
#define W2_TOT        (8 * W2_REPL_BYTES)           // 589824
#define BIAS_OFS      (W2_OFS + W2_TOT)             // b_ih+b_hh fp32[1024]
#define CONST_OFS     (BIAS_OFS + 4096)             // misc consts fp32[531]
#define CONST_N       531
#define SCR_OFS       (CONST_OFS + 4096)            // step-major outputs fp32
// scrP [12][B][2] | scrS [12][B] | scrU [12][B][2]

typedef short bf16x8 __attribute__((ext_vector_type(8)));
typedef float f32x4  __attribute__((ext_vector_type(4)));

static __device__ __forceinline__ unsigned short f2bf(float x) {
    union { float f; unsigned int u; } v; v.f = x;
    unsigned int r = v.u + 0x7FFFu + ((v.u >> 16) & 1u);   // RNE
    return (unsigned short)(r >> 16);
}
static __device__ __forceinline__ float bf2f(unsigned short u) {
    union { float f; unsigned int u; } v; v.u = ((unsigned int)u) << 16;
    return v.f;
}
static __device__ __forceinline__ float sigf(float x) { return 1.f / (1.f + __expf(-x)); }
static __device__ __forceinline__ float tanhfast(float x) {
    float e = __expf(2.f * x);
    return 1.f - 2.f / (e + 1.f);
}
static __device__ __forceinline__ int xcc_id() {
    unsigned id;
    asm volatile("s_getreg_b32 %0, hwreg(HW_REG_XCC_ID)" : "=s"(id));
    return (int)(id & 7u);
}

// ---------------- prep kernels: swizzle weights into MFMA B-fragment layout, x8 replicas -------
// frag id = p*160 + w*40 + kk*4 + g ; lane l holds W[n = g*256+p*64+w*16+(l&15)][k = kk*32+(l>>4)*8 + j]
__global__ void prep_wg(const float* __restrict__ W_ih, const float* __restrict__ W_hh,
                        unsigned char* __restrict__ ws) {
    int tid = blockIdx.x * 256 + threadIdx.x;           // 160 blocks
    int fid = tid >> 6, l = tid & 63;
    int p = fid / 160, rem = fid % 160;
    int w = rem / 40, rem2 = rem % 40;
    int kk = rem2 / 4, g = rem2 % 4;
    int n  = g * 256 + p * 64 + w * 16 + (l & 15);
    int kb = kk * 32 + (l >> 4) * 8;
    unsigned short tmp[8];
#pragma unroll
    for (int j = 0; j < 8; ++j) {
        int k = kb + j;
        float v = (k < 256) ? W_hh[n * 256 + k] : W_ih[n * 64 + (k - 256)];
        tmp[j] = f2bf(v);
    }
    unsigned short* base = (unsigned short*)(ws + WG_OFS) + (size_t)fid * 512 + l * 8;
#pragma unroll
    for (int r = 0; r < 8; ++r) {
        unsigned short* dst = base + (size_t)r * (WG_REPL_BYTES / 2);
#pragma unroll
        for (int j = 0; j < 8; ++j) dst[j] = tmp[j];
    }
}

// head-GEMM weights: n2<64 -> W_sp1, <128 -> W_un1, <130 -> W_pos, else 0. frag id = w*24+kk*3+j
__global__ void prep_w2(const float* __restrict__ W_sp1, const float* __restrict__ W_un1,
                        const float* __restrict__ W_pos, unsigned char* __restrict__ ws) {
    int tid = blockIdx.x * 256 + threadIdx.x;           // 18 blocks
    if (tid >= 72 * 64) return;
    int fid = tid >> 6, l = tid & 63;
    int w = fid / 24, rem = fid % 24;
    int kk = rem / 3, j = rem % 3;
    int n2 = w * 48 + j * 16 + (l & 15);
    int kb = kk * 32 + (l >> 4) * 8;
    unsigned short tmp[8];
#pragma unroll
    for (int jj = 0; jj < 8; ++jj) {
        int k = kb + jj;
        float v;
        if      (n2 < 64)  v = W_sp1[n2 * 256 + k];
        else if (n2 < 128) v = W_un1[(n2 - 64) * 256 + k];
        else if (n2 < 130) v = W_pos[(n2 - 128) * 256 + k];
        else               v = 0.f;
        tmp[jj] = f2bf(v);
    }
    unsigned short* base = (unsigned short*)(ws + W2_OFS) + (size_t)fid * 512 + l * 8;
#pragma unroll
    for (int r = 0; r < 8; ++r) {
        unsigned short* dst = base + (size_t)r * (W2_REPL_BYTES / 2);
#pragma unroll
        for (int jj = 0; jj < 8; ++jj) dst[jj] = tmp[jj];
    }
}

__global__ void prep_consts(const float* __restrict__ b_ih, const float* __restrict__ b_hh,
                            const float* __restrict__ W_embed, const float* __restrict__ b_embed,
                            const float* __restrict__ b_sp1, const float* __restrict__ b_un1,
                            const float* __restrict__ b_pos, const float* __restrict__ W_sp2,
                            const float* __restrict__ b_sp2, const float* __restrict__ W_un2,
                            const float* __restrict__ b_un2, unsigned char* __restrict__ ws) {
    float* biasg = (float*)(ws + BIAS_OFS);
    float* cst   = (float*)(ws + CONST_OFS);
    int t = threadIdx.x;
    for (int i = t; i < 1024; i += 256) biasg[i] = b_ih[i] + b_hh[i];
    for (int i = t; i < CONST_N; i += 256) {
        float v;
        if (i < 128) v = W_embed[i];                         // [64][2] row-major
        else if (i < 192) v = b_embed[i - 128];
        else if (i < 336) {                                  // b_su[144]: sp1 | un1 | pos | 0
            int j = i - 192;
            v = (j < 64) ? b_sp1[j] : (j < 128) ? b_un1[j - 64] : (j < 130) ? b_pos[j - 128] : 0.f;
        }
        else if (i < 400) v = W_sp2[i - 336];
        else if (i < 528) v = W_un2[i - 400];                // [2][64]
        else if (i == 528) v = b_sp2[0];
        else v = b_un2[i - 529];
        cst[i] = v;
    }
}

// ---------------- finalize: step-major scratch -> [B,12,*] outputs ----------------
__global__ void finalize(const float* __restrict__ scr, float* __restrict__ out) {
    __shared__ float sL[3840];
    int t = threadIdx.x;
    int row0 = blockIdx.x * 64;
    const float* scrP = scr;                                  // [12][B][2]
    const float* scrS = scr + (size_t)P_STEPS * B_TOT * 2;    // [12][B]
    const float* scrU = scr + (size_t)P_STEPS * B_TOT * 3;    // [12][B][2]
    for (int i = t; i < 1536; i += 256) { int st = i >> 7, j = i & 127; sL[st * 128 + j]        = scrP[(size_t)st * B_TOT * 2 + row0 * 2 + j]; }
    for (int i = t; i < 768;  i += 256) { int st = i / 64, j = i % 64;  sL[1536 + st * 64 + j]  = scrS[(size_t)st * B_TOT + row0 + j]; }
    for (int i = t; i < 1536; i += 256) { int st = i >> 7, j = i & 127; sL[2304 + st * 128 + j] = scrU[(size_t)st * B_TOT * 2 + row0 * 2 + j]; }
    __syncthreads();
    float* outP = out;
    float* outS = out + (size_t)B_TOT * 24;
    float* outU = out + (size_t)B_TOT * 36;
    for (int i = t; i < 1536; i += 256) { int r = i / 24, st = (i % 24) >> 1, d = i & 1; outP[(size_t)row0 * 24 + i] = sL[st * 128 + r * 2 + d]; }
    for (int i = t; i < 768;  i += 256) { int r = i / 12, st = i % 12;                   outS[(size_t)row0 * 12 + i] = sL[1536 + st * 64 + r]; }
    for (int i = t; i < 1536; i += 256) { int r = i / 24, st = (i % 24) >> 1, d = i & 1; outU[(size_t)row0 * 24 + i] = sL[2304 + st * 128 + r * 2 + d]; }
}

// ---------------- main persistent-scan kernel ----------------
__global__ __launch_bounds__(NTHREADS, 2)
void traj_main(const float* __restrict__ eh, const float* __restrict__ ec,
               const float* __restrict__ lp, const unsigned char* __restrict__ ws,
               float* __restrict__ scr) {
    __shared__ unsigned short sX[BT * XSTRIDE];   // [h | emb] bf16, 20992 B
    __shared__ unsigned short sH[BT * HSTRIDE];   // h_new bf16, 16896 B
    __shared__ float sPos[BT * 2];
    __shared__ float sDelta[BT * 2];
    __shared__ float sRed[2 * BT * 3];
    __shared__ float sC[536];

    const int t = threadIdx.x;
    const int w = t >> 6;
    const int l = t & 63;
    const int l15 = l & 15;
    const int quad = l >> 4;
    const int row0 = blockIdx.x * BT;
    const int repl = xcc_id();

    const bf16x8* Wg = (const bf16x8*)(ws + WG_OFS) + (size_t)repl * (WG_REPL_BYTES / 16);
    const bf16x8* W2 = (const bf16x8*)(ws + W2_OFS) + (size_t)repl * (W2_REPL_BYTES / 16);
    const float* biasg = (const float*)(ws + BIAS_OFS);
    const float* cst = (const float*)(ws + CONST_OFS);
    float* scrP = scr;                                  // [12][B][2]
    float* scrS = scr + (size_t)P_STEPS * B_TOT * 2;    // [12][B]
    float* scrU = scr + (size_t)P_STEPS * B_TOT * 3;    // [12][B][2]

    // ---- prologue ----
    for (int i = t; i < CONST_N; i += NTHREADS) sC[i] = cst[i];
#pragma unroll
    for (int r = 0; r < BT; ++r)
        sX[r * XSTRIDE + t] = f2bf(eh[(size_t)(row0 + r) * H_DIM + t]);
    if (t < BT * 2) sPos[t] = lp[row0 * 2 + t];

    float creg[NPASS][MT][4];                         // cell state, fp32 (accum-side regs)
    float breg[NPASS][4];                             // gate biases for this lane's col
#pragma unroll
    for (int p = 0; p < NPASS; ++p) {
        int col = p * 64 + w * 16 + l15;
#pragma unroll
        for (int g = 0; g < 4; ++g) breg[p][g] = biasg[g * 256 + col];
#pragma unroll
        for (int mi = 0; mi < MT; ++mi)
#pragma unroll
            for (int rr = 0; rr < 4; ++rr)
                creg[p][mi][rr] = ec[(size_t)(row0 + (mi * 16 + quad * 4 + rr)) * H_DIM + col];
    }

    auto do_emb = [&]() {   // emb = relu(pos @ W_embed^T + b_embed) -> X cols 256..319
        int r = t >> 3, eb = (t & 7) * 8;             // 8 threads/row, 8 cols each
        float p0 = sPos[r * 2], p1 = sPos[r * 2 + 1];
#pragma unroll
        for (int e = 0; e < 8; ++e) {
            int ecol = eb + e;
            float v = p0 * sC[ecol * 2] + p1 * sC[ecol * 2 + 1] + sC[128 + ecol];
            sX[r * XSTRIDE + 256 + ecol] = f2bf(fmaxf(v, 0.f));
        }
    };

    __syncthreads();          // sPos/consts ready
    do_emb();

    for (int st = 0; st < P_STEPS; ++st) {
        // ---- GEMM1: gates = X @ [W_hh|W_ih]^T; 3-buffer distance-2 B prefetch from L2 ----
        bf16x8 bvbuf[3][4];
        auto ldB1 = [&](int idx, int slot) {          // idx = flat (p,kk), compile-time
            int p = idx / KK1, kk = idx % KK1;
            size_t f = (size_t)(((p * 4 + w) * 40 + kk * 4)) * 64 + l;
#pragma unroll
            for (int g = 0; g < 4; ++g) bvbuf[slot][g] = Wg[f + (size_t)g * 64];
        };
        ldB1(0, 0); ldB1(1, 1);       // prime before barrier (global, no LDS dep)

        __syncthreads();      // B1: X = [h | emb] consistent

        ldB1(2, 2);
        bf16x8 av[2][MT];
#pragma unroll
        for (int mi = 0; mi < MT; ++mi)
            av[0][mi] = *(const bf16x8*)(&sX[(mi * 16 + l15) * XSTRIDE + quad * 8]);

#pragma unroll
        for (int p = 0; p < NPASS; ++p) {
            f32x4 acc[MT][4];
#pragma unroll
            for (int mi = 0; mi < MT; ++mi)
#pragma unroll
                for (int g = 0; g < 4; ++g) acc[mi][g] = f32x4{0.f, 0.f, 0.f, 0.f};
#pragma unroll
            for (int kk = 0; kk < KK1; ++kk) {
                const int idx = p * KK1 + kk;
                const int cb = idx & 1, nb = cb ^ 1;
                if (idx + 1 < NIT) {                  // A-frag prefetch (LDS, distance 1)
                    const int nkk = (idx + 1) % KK1;
#pragma unroll
                    for (int mi = 0; mi < MT; ++mi)
                        av[nb][mi] = *(const bf16x8*)(&sX[(mi * 16 + l15) * XSTRIDE + nkk * 32 + quad * 8]);
                }
#pragma unroll
                for (int mi = 0; mi < MT; ++mi)
#pragma unroll
                    for (int g = 0; g < 4; ++g)
                        acc[mi][g] = __builtin_amdgcn_mfma_f32_16x16x32_bf16(av[cb][mi], bvbuf[idx % 3][g], acc[mi][g], 0, 0, 0);
                if (idx + 3 < NIT) ldB1(idx + 3, idx % 3);   // slot freed by this iter's MFMAs
            }
            // LSTM pointwise epilogue
#pragma unroll
            for (int mi = 0; mi < MT; ++mi)
#pragma unroll
                for (int rr = 0; rr < 4; ++rr) {
                    float iv = acc[mi][0][rr] + breg[p][0];
                    float fv = acc[mi][1][rr] + breg[p][1];
                    float gv = acc[mi][2][rr] + breg[p][2];
                    float ov = acc[mi][3][rr] + breg[p][3];
                    float cn = sigf(fv) * creg[p][mi][rr] + sigf(iv) * tanhfast(gv);
                    float hv = sigf(ov) * tanhfast(cn);
                    creg[p][mi][rr] = cn;
                    int r = mi * 16 + quad * 4 + rr;
                    sH[r * HSTRIDE + (p * 64 + w * 16 + l15)] = f2bf(hv);
                }
        }

        // ---- GEMM2 prefetch (global, no LDS dep -> before barrier) ----
        bf16x8 b2buf[2][3];
        auto ldB2 = [&](int kk, int slot) {
#pragma unroll
            for (int j = 0; j < 3; ++j) b2buf[slot][j] = W2[(size_t)(w * 24 + kk * 3 + j) * 64 + l];
        };
        if (w < 3) { ldB2(0, 0); ldB2(1, 1); }

        __syncthreads();      // B2: h_new complete

        // ---- GEMM2: heads = h_new @ [W_sp1|W_un1|W_pos]^T (waves 0..2; N=144) ----
        if (w < 3) {
            f32x4 acc2[MT][3];
#pragma unroll
            for (int mi = 0; mi < MT; ++mi)
#pragma unroll
                for (int j = 0; j < 3; ++j) acc2[mi][j] = f32x4{0.f, 0.f, 0.f, 0.f};
#pragma unroll
            for (int kk = 0; kk < KK2; ++kk) {
                bf16x8 a2[MT];
#pragma unroll
                for (int mi = 0; mi < MT; ++mi)
                    a2[mi] = *(const bf16x8*)(&sH[(mi * 16 + l15) * HSTRIDE + kk * 32 + quad * 8]);
#pragma unroll
                for (int mi = 0; mi < MT; ++mi)
#pragma unroll
                    for (int j = 0; j < 3; ++j)
                        acc2[mi][j] = __builtin_amdgcn_mfma_f32_16x16x32_bf16(a2[mi], b2buf[kk & 1][j], acc2[mi][j], 0, 0, 0);
                if (kk + 2 < KK2) ldB2(kk + 2, kk & 1);
            }
#pragma unroll
            for (int j = 0; j < 3; ++j) {
                int col2 = w * 48 + j * 16 + l15;
                float bb = sC[192 + col2];
#pragma unroll
                for (int mi = 0; mi < MT; ++mi)
#pragma unroll
                    for (int rr = 0; rr < 4; ++rr) {
                        float v = acc2[mi][j][rr] + bb;
                        int r = mi * 16 + quad * 4 + rr;
                        if (col2 < 128) v = fmaxf(v, 0.f);
                        else if (col2 < 130) sDelta[r * 2 + (col2 - 128)] = v;
                        sX[r * XSTRIDE + col2] = f2bf(v);       // heads alias dead X h-region
                    }
            }
        }
        __syncthreads();      // B3: heads + delta ready

        // ---- head dots + prediction output + pos update ----
        if (t < 2 * BT) {
            int r = t & (BT - 1), part = t >> 5, k0 = part * 32;
            float s0 = 0.f, s1 = 0.f, s2 = 0.f;
#pragma unroll
            for (int v8 = 0; v8 < 4; ++v8) {
                bf16x8 hs8 = *(const bf16x8*)(&sX[r * XSTRIDE + k0 + v8 * 8]);
                bf16x8 hu8 = *(const bf16x8*)(&sX[r * XSTRIDE + 64 + k0 + v8 * 8]);
#pragma unroll
                for (int k = 0; k < 8; ++k) {
                    float hs = bf2f((unsigned short)hs8[k]);
                    float hu = bf2f((unsigned short)hu8[k]);
                    int kc = k0 + v8 * 8 + k;
                    s0 += hs * sC[336 + kc];
                    s1 += hu * sC[400 + kc];
                    s2 += hu * sC[464 + kc];
                }
            }
            sRed[(part * BT + r) * 3 + 0] = s0;
            sRed[(part * BT + r) * 3 + 1] = s1;
            sRed[(part * BT + r) * 3 + 2] = s2;

            int rp = t >> 1, d = t & 1;
            float pv = sPos[rp * 2 + d] + sDelta[rp * 2 + d];
            scrP[(size_t)st * B_TOT * 2 + row0 * 2 + t] = pv;   // coalesced
            sPos[rp * 2 + d] = pv;
        }
        __syncthreads();      // B4: partials + new pos ready

        if (t < BT) {
            int r = t;
            float sp = sRed[r * 3] + sRed[(BT + r) * 3] + sC[528];
            sp = fmaxf(sp, 0.f) + log1pf(__expf(-fabsf(sp)));     // stable softplus
            scrS[(size_t)st * B_TOT + row0 + t] = sp;
            float u0 = __expf(sRed[r * 3 + 1] + sRed[(BT + r) * 3 + 1] + sC[529]);
            float u1 = __expf(sRed[r * 3 + 2] + sRed[(BT + r) * 3 + 2] + sC[530]);
            scrU[(size_t)st * B_TOT * 2 + row0 * 2 + 2 * t]     = u0;
            scrU[(size_t)st * B_TOT * 2 + row0 * 2 + 2 * t + 1] = u1;
        }
        if (st < P_STEPS - 1) {
            // copy h_new -> X h-region (vectorized), then new emb
#pragma unroll
            for (int i = 0; i < 4; ++i) {
                int gidx = i * NTHREADS + t;                    // 1024 vec8 chunks
                int r = gidx >> 5, c8 = (gidx & 31) * 8;
                *(bf16x8*)(&sX[r * XSTRIDE + c8]) = *(const bf16x8*)(&sH[r * HSTRIDE + c8]);
            }
            do_emb();
        }
    }
}

extern "C" void kernel_launch(void* const* d_in, const int* in_sizes, int n_in,
                              void* d_out, int out_size, void* d_ws, size_t ws_size,
                              hipStream_t stream) {
    (void)in_sizes; (void)n_in; (void)out_size; (void)ws_size;
    const float* eh      = (const float*)d_in[0];
    const float* ec      = (const float*)d_in[1];
    const float* lp      = (const float*)d_in[2];
    const float* W_embed = (const float*)d_in[3];
    const float* b_embed = (const float*)d_in[4];
    const float* W_ih    = (const float*)d_in[5];
    const float* W_hh    = (const float*)d_in[6];
    const float* b_ih    = (const float*)d_in[7];
    const float* b_hh    = (const float*)d_in[8];
    const float* W_pos   = (const float*)d_in[9];
    const float* b_pos   = (const float*)d_in[10];
    const float* W_sp1   = (const float*)d_in[11];
    const float* b_sp1   = (const float*)d_in[12];
    const float* W_sp2   = (const float*)d_in[13];
    const float* b_sp2   = (const float*)d_in[14];
    const float* W_un1   = (const float*)d_in[15];
    const float* b_un1   = (const float*)d_in[16];
    const float* W_un2   = (const float*)d_in[17];
    const float* b_un2   = (const float*)d_in[18];
    unsigned char* ws = (unsigned char*)d_ws;
    float* out = (float*)d_out;
    float* scr = (float*)(ws + SCR_OFS);

    hipLaunchKernelGGL(prep_wg, dim3(160), dim3(256), 0, stream, W_ih, W_hh, ws);
    hipLaunchKernelGGL(prep_w2, dim3(18), dim3(256), 0, stream, W_sp1, W_un1, W_pos, ws);
    hipLaunchKernelGGL(prep_consts, dim3(1), dim3(256), 0, stream, b_ih, b_hh, W_embed, b_embed,
                       b_sp1, b_un1, b_pos, W_sp2, b_sp2, W_un2, b_un2, ws);
    hipLaunchKernelGGL(traj_main, dim3(B_TOT / BT), dim3(NTHREADS), 0, stream, eh, ec, lp, ws, scr);
    hipLaunchKernelGGL(finalize, dim3(B_TOT / 64), dim3(256), 0, stream, scr, out);
}

// Round 6
// 1015.464 us; speedup vs baseline: 3.7204x; 3.7204x over previous
//
#include <hip/hip_runtime.h>
#include <stdint.h>

// Problem constants
#define B_TOT    65536
#define H_DIM    256
#define E_DIM    64
#define P_STEPS  12

// Config: 64-row batch tile, 4 waves, 2 WGs/CU, one kernel launch per step
#define BT       64
#define NTHREADS 256
#define MT       4          // 16-row M tiles per wave (BT/16)
#define NPASS    4          // hidden passes (64 hidden cols each)
#define KK1      10         // K=320 / 32
#define KK2      8          // K=256 / 32
#define NIT      (NPASS * KK1)   // 40 flat GEMM1 iters

#define XSTRIDE  328        // 320 + 8 pad (bf16 elems)
#define HSTRIDE  264        // 256 + 8 pad

// workspace layout (bytes)
#define WG_OFS        0
#define WG_REPL_BYTES (640 * 1024)                  // 640 frags x 1KB
#define WG_TOT        (8 * WG_REPL_BYTES)           // 5242880
#define W2_OFS        WG_TOT
#define W2_REPL_BYTES (72 * 1024)
#define W2_TOT        (8 * W2_REPL_BYTES)           // 589824
#define BIAS_OFS      (W2_OFS + W2_TOT)             // b_ih+b_hh fp32[1024]
#define CONST_OFS     (BIAS_OFS + 4096)             // misc consts fp32[531]
#define CONST_N       531
#define SCR_OFS       (CONST_OFS + 4096)
#define SCR_BYTES     (P_STEPS * B_TOT * 5 * 4)     // 15728640: P[12][B][2] S[12][B] U[12][B][2]
#define HBUF_OFS      (SCR_OFS + SCR_BYTES)
#define HBUF_BYTES    (B_TOT * H_DIM * 2)           // bf16 h state
#define CBUF_OFS      (HBUF_OFS + HBUF_BYTES)
#define CBUF_BYTES    (B_TOT * H_DIM * 2)           // bf16 c state (swizzled layout)
#define POS_OFS       (CBUF_OFS + CBUF_BYTES)
#define POS_BYTES     (B_TOT * 2 * 4)               // two ping-pong pos buffers follow

typedef short bf16x8 __attribute__((ext_vector_type(8)));
typedef float f32x4  __attribute__((ext_vector_type(4)));

static __device__ __forceinline__ unsigned short f2bf(float x) {
    union { float f; unsigned int u; } v; v.f = x;
    unsigned int r = v.u + 0x7FFFu + ((v.u >> 16) & 1u);   // RNE
    return (unsigned short)(r >> 16);
}
static __device__ __forceinline__ float bf2f(unsigned short u) {
    union { float f; unsigned int u; } v; v.u = ((unsigned int)u) << 16;
    return v.f;
}
// division-free: v_rcp_f32 (~1ulp), v_exp_f32 via __expf
static __device__ __forceinline__ float sigf(float x) {
    return __builtin_amdgcn_rcpf(1.f + __expf(-x));
}
static __device__ __forceinline__ float tanhfast(float x) {
    float e = __expf(2.f * x);
    return 1.f - 2.f * __builtin_amdgcn_rcpf(e + 1.f);
}
static __device__ __forceinline__ int xcc_id() {
    unsigned id;
    asm volatile("s_getreg_b32 %0, hwreg(HW_REG_XCC_ID)" : "=s"(id));
    return (int)(id & 7u);
}

// ---------------- prep kernels (unchanged swizzle, x8 replicas) ----------------
__global__ void prep_wg(const float* __restrict__ W_ih, const float* __restrict__ W_hh,
                        unsigned char* __restrict__ ws) {
    int tid = blockIdx.x * 256 + threadIdx.x;           // 160 blocks
    int fid = tid >> 6, l = tid & 63;
    int p = fid / 160, rem = fid % 160;
    int w = rem / 40, rem2 = rem % 40;
    int kk = rem2 / 4, g = rem2 % 4;
    int n  = g * 256 + p * 64 + w * 16 + (l & 15);
    int kb = kk * 32 + (l >> 4) * 8;
    unsigned short tmp[8];
#pragma unroll
    for (int j = 0; j < 8; ++j) {
        int k = kb + j;
        float v = (k < 256) ? W_hh[n * 256 + k] : W_ih[n * 64 + (k - 256)];
        tmp[j] = f2bf(v);
    }
    unsigned short* base = (unsigned short*)(ws + WG_OFS) + (size_t)fid * 512 + l * 8;
#pragma unroll
    for (int r = 0; r < 8; ++r) {
        unsigned short* dst = base + (size_t)r * (WG_REPL_BYTES / 2);
#pragma unroll
        for (int j = 0; j < 8; ++j) dst[j] = tmp[j];
    }
}

__global__ void prep_w2(const float* __restrict__ W_sp1, const float* __restrict__ W_un1,
                        const float* __restrict__ W_pos, unsigned char* __restrict__ ws) {
    int tid = blockIdx.x * 256 + threadIdx.x;           // 18 blocks
    if (tid >= 72 * 64) return;
    int fid = tid >> 6, l = tid & 63;
    int w = fid / 24, rem = fid % 24;
    int kk = rem / 3, j = rem % 3;
    int n2 = w * 48 + j * 16 + (l & 15);
    int kb = kk * 32 + (l >> 4) * 8;
    unsigned short tmp[8];
#pragma unroll
    for (int jj = 0; jj < 8; ++jj) {
        int k = kb + jj;
        float v;
        if      (n2 < 64)  v = W_sp1[n2 * 256 + k];
        else if (n2 < 128) v = W_un1[(n2 - 64) * 256 + k];
        else if (n2 < 130) v = W_pos[(n2 - 128) * 256 + k];
        else               v = 0.f;
        tmp[jj] = f2bf(v);
    }
    unsigned short* base = (unsigned short*)(ws + W2_OFS) + (size_t)fid * 512 + l * 8;
#pragma unroll
    for (int r = 0; r < 8; ++r) {
        unsigned short* dst = base + (size_t)r * (W2_REPL_BYTES / 2);
#pragma unroll
        for (int jj = 0; jj < 8; ++jj) dst[jj] = tmp[jj];
    }
}

__global__ void prep_consts(const float* __restrict__ b_ih, const float* __restrict__ b_hh,
                            const float* __restrict__ W_embed, const float* __restrict__ b_embed,
                            const float* __restrict__ b_sp1, const float* __restrict__ b_un1,
                            const float* __restrict__ b_pos, const float* __restrict__ W_sp2,
                            const float* __restrict__ b_sp2, const float* __restrict__ W_un2,
                            const float* __restrict__ b_un2, unsigned char* __restrict__ ws) {
    float* biasg = (float*)(ws + BIAS_OFS);
    float* cst   = (float*)(ws + CONST_OFS);
    int t = threadIdx.x;
    for (int i = t; i < 1024; i += 256) biasg[i] = b_ih[i] + b_hh[i];
    for (int i = t; i < CONST_N; i += 256) {
        float v;
        if (i < 128) v = W_embed[i];
        else if (i < 192) v = b_embed[i - 128];
        else if (i < 336) {
            int j = i - 192;
            v = (j < 64) ? b_sp1[j] : (j < 128) ? b_un1[j - 64] : (j < 130) ? b_pos[j - 128] : 0.f;
        }
        else if (i < 400) v = W_sp2[i - 336];
        else if (i < 528) v = W_un2[i - 400];
        else if (i == 528) v = b_sp2[0];
        else v = b_un2[i - 529];
        cst[i] = v;
    }
}

// ---------------- finalize: step-major scratch -> [B,12,*] outputs ----------------
__global__ void finalize(const float* __restrict__ scr, float* __restrict__ out) {
    __shared__ float sL[3840];
    int t = threadIdx.x;
    int row0 = blockIdx.x * 64;
    const float* scrP = scr;
    const float* scrS = scr + (size_t)P_STEPS * B_TOT * 2;
    const float* scrU = scr + (size_t)P_STEPS * B_TOT * 3;
    for (int i = t; i < 1536; i += 256) { int st = i >> 7, j = i & 127; sL[st * 128 + j]        = scrP[(size_t)st * B_TOT * 2 + row0 * 2 + j]; }
    for (int i = t; i < 768;  i += 256) { int st = i / 64, j = i % 64;  sL[1536 + st * 64 + j]  = scrS[(size_t)st * B_TOT + row0 + j]; }
    for (int i = t; i < 1536; i += 256) { int st = i >> 7, j = i & 127; sL[2304 + st * 128 + j] = scrU[(size_t)st * B_TOT * 2 + row0 * 2 + j]; }
    __syncthreads();
    float* outP = out;
    float* outS = out + (size_t)B_TOT * 24;
    float* outU = out + (size_t)B_TOT * 36;
    for (int i = t; i < 1536; i += 256) { int r = i / 24, st = (i % 24) >> 1, d = i & 1; outP[(size_t)row0 * 24 + i] = sL[st * 128 + r * 2 + d]; }
    for (int i = t; i < 768;  i += 256) { int r = i / 12, st = i % 12;                   outS[(size_t)row0 * 12 + i] = sL[1536 + st * 64 + r]; }
    for (int i = t; i < 1536; i += 256) { int r = i / 24, st = (i % 24) >> 1, d = i & 1; outU[(size_t)row0 * 24 + i] = sL[2304 + st * 128 + r * 2 + d]; }
}

// ---------------- one LSTM step (launched 12x) ----------------
__global__ __launch_bounds__(NTHREADS, 2)
void traj_step(int st, const float* __restrict__ eh, const float* __restrict__ ec,
               const float* __restrict__ posIn, float* __restrict__ posOut,
               unsigned char* __restrict__ ws, float* __restrict__ scr) {
    __shared__ unsigned short sX[BT * XSTRIDE];   // [h | emb] bf16, 41984 B
    __shared__ unsigned short sH[BT * HSTRIDE];   // h_new bf16, 33792 B
    __shared__ float sPos[BT * 2];
    __shared__ float sDelta[BT * 2];
    __shared__ float sRed[2 * BT * 3];
    __shared__ float sC[536];

    const int t = threadIdx.x;
    const int w = t >> 6;
    const int l = t & 63;
    const int l15 = l & 15;
    const int quad = l >> 4;
    const int row0 = blockIdx.x * BT;
    const int repl = xcc_id();

    const bf16x8* Wg = (const bf16x8*)(ws + WG_OFS) + (size_t)repl * (WG_REPL_BYTES / 16);
    const bf16x8* W2 = (const bf16x8*)(ws + W2_OFS) + (size_t)repl * (W2_REPL_BYTES / 16);
    const float* biasg = (const float*)(ws + BIAS_OFS);
    const float* cst = (const float*)(ws + CONST_OFS);
    unsigned short* hbuf = (unsigned short*)(ws + HBUF_OFS);
    unsigned short* cbuf = (unsigned short*)(ws + CBUF_OFS);
    float* scrP = scr;
    float* scrS = scr + (size_t)P_STEPS * B_TOT * 2;
    float* scrU = scr + (size_t)P_STEPS * B_TOT * 3;

    // ---- stage consts, pos, h ----
    for (int i = t; i < CONST_N; i += NTHREADS) sC[i] = cst[i];
    if (t < BT * 2) sPos[t] = posIn[row0 * 2 + t];
    if (st == 0) {
#pragma unroll 8
        for (int r = 0; r < BT; ++r)
            sX[r * XSTRIDE + t] = f2bf(eh[(size_t)(row0 + r) * H_DIM + t]);   // coalesced
    } else {
        const bf16x8* h8 = (const bf16x8*)(hbuf + (size_t)row0 * H_DIM);
#pragma unroll
        for (int i = 0; i < 8; ++i) {
            int idx = i * NTHREADS + t;                 // 2048 chunks
            int r = idx >> 5, c = idx & 31;
            *(bf16x8*)(&sX[r * XSTRIDE + c * 8]) = h8[idx];
        }
    }
    __syncthreads();

    // emb = relu(pos @ W_embed^T + b_embed) -> sX cols 256..319
    {
        int r = t >> 2, eb = (t & 3) * 16;
        float p0 = sPos[r * 2], p1 = sPos[r * 2 + 1];
#pragma unroll
        for (int e = 0; e < 16; ++e) {
            int ecol = eb + e;
            float v = p0 * sC[ecol * 2] + p1 * sC[ecol * 2 + 1] + sC[128 + ecol];
            sX[r * XSTRIDE + 256 + ecol] = f2bf(fmaxf(v, 0.f));
        }
    }

    // ---- GEMM1: gates = X @ [W_hh|W_ih]^T, fused LSTM pointwise ----
    bf16x8 bvbuf[3][4];
    auto ldB1 = [&](int idx, int slot) {
        int p = idx / KK1, kk = idx % KK1;
        size_t f = (size_t)(((p * 4 + w) * 40 + kk * 4)) * 64 + l;
#pragma unroll
        for (int g = 0; g < 4; ++g) bvbuf[slot][g] = Wg[f + (size_t)g * 64];
    };
    ldB1(0, 0); ldB1(1, 1);
    __syncthreads();          // B1: sX complete
    ldB1(2, 2);

    bf16x8 av[2][MT];
#pragma unroll
    for (int mi = 0; mi < MT; ++mi)
        av[0][mi] = *(const bf16x8*)(&sX[(mi * 16 + l15) * XSTRIDE + quad * 8]);

#pragma unroll
    for (int p = 0; p < NPASS; ++p) {
        const int col = p * 64 + w * 16 + l15;
        const size_t cb = ((size_t)blockIdx.x * NPASS + p) * 4096 + (size_t)w * 1024 + l;
        // issue c + bias loads up front; consumed after the MFMA loop (latency hidden)
        float cfl[16], bg[4];
        if (st == 0) {
#pragma unroll
            for (int mi = 0; mi < MT; ++mi)
#pragma unroll
                for (int rr = 0; rr < 4; ++rr)
                    cfl[mi * 4 + rr] = ec[(size_t)(row0 + mi * 16 + quad * 4 + rr) * H_DIM + col];
        } else {
#pragma unroll
            for (int e = 0; e < 16; ++e) cfl[e] = bf2f(cbuf[cb + e * 64]);
        }
#pragma unroll
        for (int g = 0; g < 4; ++g) bg[g] = biasg[g * 256 + col];

        f32x4 acc[MT][4];
#pragma unroll
        for (int mi = 0; mi < MT; ++mi)
#pragma unroll
            for (int g = 0; g < 4; ++g) acc[mi][g] = f32x4{0.f, 0.f, 0.f, 0.f};
#pragma unroll
        for (int kk = 0; kk < KK1; ++kk) {
            const int idx = p * KK1 + kk;
            const int cbi = idx & 1, nb = cbi ^ 1;
            if (idx + 1 < NIT) {
                const int nkk = (idx + 1) % KK1;
#pragma unroll
                for (int mi = 0; mi < MT; ++mi)
                    av[nb][mi] = *(const bf16x8*)(&sX[(mi * 16 + l15) * XSTRIDE + nkk * 32 + quad * 8]);
            }
#pragma unroll
            for (int mi = 0; mi < MT; ++mi)
#pragma unroll
                for (int g = 0; g < 4; ++g)
                    acc[mi][g] = __builtin_amdgcn_mfma_f32_16x16x32_bf16(av[cbi][mi], bvbuf[idx % 3][g], acc[mi][g], 0, 0, 0);
            if (idx + 3 < NIT) ldB1(idx + 3, idx % 3);
        }
        // LSTM pointwise (division-free)
#pragma unroll
        for (int mi = 0; mi < MT; ++mi)
#pragma unroll
            for (int rr = 0; rr < 4; ++rr) {
                const int e = mi * 4 + rr;
                float iv = acc[mi][0][rr] + bg[0];
                float fv = acc[mi][1][rr] + bg[1];
                float gv = acc[mi][2][rr] + bg[2];
                float ov = acc[mi][3][rr] + bg[3];
                float cn = sigf(fv) * cfl[e] + sigf(iv) * tanhfast(gv);
                float hv = sigf(ov) * tanhfast(cn);
                if (st < P_STEPS - 1) cbuf[cb + e * 64] = f2bf(cn);   // coalesced 128B lines
                sH[(mi * 16 + quad * 4 + rr) * HSTRIDE + col] = f2bf(hv);
            }
    }

    // ---- GEMM2 prefetch (waves 0..2), before barrier ----
    bf16x8 b2buf[2][3];
    auto ldB2 = [&](int kk, int slot) {
#pragma unroll
        for (int j = 0; j < 3; ++j) b2buf[slot][j] = W2[(size_t)(w * 24 + kk * 3 + j) * 64 + l];
    };
    if (w < 3) { ldB2(0, 0); ldB2(1, 1); }

    __syncthreads();          // B2: h_new complete

    if (w == 3) {
        // wave 3: write h_out while waves 0-2 run GEMM2
        if (st < P_STEPS - 1) {
            unsigned short* hout = hbuf + (size_t)row0 * H_DIM;
#pragma unroll
            for (int i = 0; i < 32; ++i) {
                int idx = i * 64 + l;                   // 2048 chunks
                int r = idx >> 5, c = idx & 31;
                *(bf16x8*)(&hout[(size_t)r * H_DIM + c * 8]) = *(const bf16x8*)(&sH[r * HSTRIDE + c * 8]);
            }
        }
    } else {
        // GEMM2: heads = h_new @ [W_sp1|W_un1|W_pos]^T (N=144)
        f32x4 acc2[MT][3];
#pragma unroll
        for (int mi = 0; mi < MT; ++mi)
#pragma unroll
            for (int j = 0; j < 3; ++j) acc2[mi][j] = f32x4{0.f, 0.f, 0.f, 0.f};
#pragma unroll
        for (int kk = 0; kk < KK2; ++kk) {
            bf16x8 a2[MT];
#pragma unroll
            for (int mi = 0; mi < MT; ++mi)
                a2[mi] = *(const bf16x8*)(&sH[(mi * 16 + l15) * HSTRIDE + kk * 32 + quad * 8]);
#pragma unroll
            for (int mi = 0; mi < MT; ++mi)
#pragma unroll
                for (int j = 0; j < 3; ++j)
                    acc2[mi][j] = __builtin_amdgcn_mfma_f32_16x16x32_bf16(a2[mi], b2buf[kk & 1][j], acc2[mi][j], 0, 0, 0);
            if (kk + 2 < KK2) ldB2(kk + 2, kk & 1);
        }
#pragma unroll
        for (int j = 0; j < 3; ++j) {
            int col2 = w * 48 + j * 16 + l15;
            float bb = sC[192 + col2];
#pragma unroll
            for (int mi = 0; mi < MT; ++mi)
#pragma unroll
                for (int rr = 0; rr < 4; ++rr) {
                    float v = acc2[mi][j][rr] + bb;
                    int r = mi * 16 + quad * 4 + rr;
                    if (col2 < 128) v = fmaxf(v, 0.f);
                    else if (col2 < 130) sDelta[r * 2 + (col2 - 128)] = v;
                    sX[r * XSTRIDE + col2] = f2bf(v);       // heads alias dead X h-region
                }
        }
    }
    __syncthreads();          // B3: heads + delta ready

    // ---- head dots + prediction + pos ----
    if (t < 128) {
        int r = t & 63, part = t >> 6, k0 = part * 32;
        float s0 = 0.f, s1 = 0.f, s2 = 0.f;
#pragma unroll
        for (int v8 = 0; v8 < 4; ++v8) {
            bf16x8 hs8 = *(const bf16x8*)(&sX[r * XSTRIDE + k0 + v8 * 8]);
            bf16x8 hu8 = *(const bf16x8*)(&sX[r * XSTRIDE + 64 + k0 + v8 * 8]);
#pragma unroll
            for (int k = 0; k < 8; ++k) {
                float hs = bf2f((unsigned short)hs8[k]);
                float hu = bf2f((unsigned short)hu8[k]);
                int kc = k0 + v8 * 8 + k;
                s0 += hs * sC[336 + kc];
                s1 += hu * sC[400 + kc];
                s2 += hu * sC[464 + kc];
            }
        }
        sRed[(part * 64 + r) * 3 + 0] = s0;
        sRed[(part * 64 + r) * 3 + 1] = s1;
        sRed[(part * 64 + r) * 3 + 2] = s2;

        int rp = t >> 1, d = t & 1;
        float pv = sPos[rp * 2 + d] + sDelta[rp * 2 + d];
        scrP[(size_t)st * B_TOT * 2 + row0 * 2 + t] = pv;
        posOut[row0 * 2 + t] = pv;
    }
    __syncthreads();          // B4

    if (t < 64) {
        int r = t;
        float sp = sRed[r * 3] + sRed[(64 + r) * 3] + sC[528];
        sp = fmaxf(sp, 0.f) + log1pf(__expf(-fabsf(sp)));     // stable softplus
        scrS[(size_t)st * B_TOT + row0 + t] = sp;
        float u0 = __expf(sRed[r * 3 + 1] + sRed[(64 + r) * 3 + 1] + sC[529]);
        float u1 = __expf(sRed[r * 3 + 2] + sRed[(64 + r) * 3 + 2] + sC[530]);
        scrU[(size_t)st * B_TOT * 2 + row0 * 2 + 2 * t]     = u0;
        scrU[(size_t)st * B_TOT * 2 + row0 * 2 + 2 * t + 1] = u1;
    }
}

extern "C" void kernel_launch(void* const* d_in, const int* in_sizes, int n_in,
                              void* d_out, int out_size, void* d_ws, size_t ws_size,
                              hipStream_t stream) {
    (void)in_sizes; (void)n_in; (void)out_size; (void)ws_size;
    const float* eh      = (const float*)d_in[0];
    const float* ec      = (const float*)d_in[1];
    const float* lp      = (const float*)d_in[2];
    const float* W_embed = (const float*)d_in[3];
    const float* b_embed = (const float*)d_in[4];
    const float* W_ih    = (const float*)d_in[5];
    const float* W_hh    = (const float*)d_in[6];
    const float* b_ih    = (const float*)d_in[7];
    const float* b_hh    = (const float*)d_in[8];
    const float* W_pos   = (const float*)d_in[9];
    const float* b_pos   = (const float*)d_in[10];
    const float* W_sp1   = (const float*)d_in[11];
    const float* b_sp1   = (const float*)d_in[12];
    const float* W_sp2   = (const float*)d_in[13];
    const float* b_sp2   = (const float*)d_in[14];
    const float* W_un1   = (const float*)d_in[15];
    const float* b_un1   = (const float*)d_in[16];
    const float* W_un2   = (const float*)d_in[17];
    const float* b_un2   = (const float*)d_in[18];
    unsigned char* ws = (unsigned char*)d_ws;
    float* out = (float*)d_out;
    float* scr = (float*)(ws + SCR_OFS);

    hipLaunchKernelGGL(prep_wg, dim3(160), dim3(256), 0, stream, W_ih, W_hh, ws);
    hipLaunchKernelGGL(prep_w2, dim3(18), dim3(256), 0, stream, W_sp1, W_un1, W_pos, ws);
    hipLaunchKernelGGL(prep_consts, dim3(1), dim3(256), 0, stream, b_ih, b_hh, W_embed, b_embed,
                       b_sp1, b_un1, b_pos, W_sp2, b_sp2, W_un2, b_un2, ws);

    for (int st = 0; st < P_STEPS; ++st) {
        const float* posIn = (st == 0) ? lp
                           : (const float*)(ws + POS_OFS + (size_t)(st & 1) * POS_BYTES);
        float* posOut = (float*)(ws + POS_OFS + (size_t)((st + 1) & 1) * POS_BYTES);
        hipLaunchKernelGGL(traj_step, dim3(B_TOT / BT), dim3(NTHREADS), 0, stream,
                           st, eh, ec, posIn, posOut, ws, scr);
    }
    hipLaunchKernelGGL(finalize, dim3(B_TOT / 64), dim3(256), 0, stream, scr, out);
}